// Round 14
// baseline (126.385 us; speedup 1.0000x reference)
//
#include <hip/hip_runtime.h>

#define N_ROWS 8192
#define DIM 256
#define EPSF 1e-8f

typedef _Float16 f16x8 __attribute__((ext_vector_type(8)));
typedef float f32x4 __attribute__((ext_vector_type(4)));

// ---------------------------------------------------------------------------
// D1: inv_norm (fp32) + fp64 column-sums of x_hat via LDS reduce + one
// f64 atomicAdd per thread (proven r1-r13).  512 blocks x 16 rows.
// ---------------------------------------------------------------------------
__global__ __launch_bounds__(256) void k1_norm(const float* __restrict__ T,
                                               float* __restrict__ inv_norm,
                                               double* __restrict__ s) {
    __shared__ double sacc[4][DIM];
    const int tid = threadIdx.x, bid = blockIdx.x;
    const int lane = tid & 63, wave = tid >> 6;
    double a0 = 0, a1 = 0, a2 = 0, a3 = 0;
#pragma unroll
    for (int r = 0; r < 4; ++r) {
        int row = bid * 16 + wave * 4 + r;
        float4 v = ((const float4*)(T + (size_t)row * DIM))[lane];
        float ss = v.x * v.x + v.y * v.y + v.z * v.z + v.w * v.w;
#pragma unroll
        for (int o = 32; o; o >>= 1) ss += __shfl_down(ss, o);
        ss = __shfl(ss, 0);
        float inv = 1.0f / fmaxf(sqrtf(ss), EPSF);
        if (lane == 0) inv_norm[row] = inv;
        a0 += (double)(v.x * inv);
        a1 += (double)(v.y * inv);
        a2 += (double)(v.z * inv);
        a3 += (double)(v.w * inv);
    }
    sacc[wave][lane * 4 + 0] = a0;
    sacc[wave][lane * 4 + 1] = a1;
    sacc[wave][lane * 4 + 2] = a2;
    sacc[wave][lane * 4 + 3] = a3;
    __syncthreads();
    double t = sacc[0][tid] + sacc[1][tid] + sacc[2][tid] + sacc[3][tid];
    atomicAdd(&s[tid], t);
}

// ---------------------------------------------------------------------------
// D2: M-GEMM only (512 blocks, split-K 32, r10-verified schedule), but the
// epilogue atomically accumulates fp32 Mt[d][k] (TRANSPOSED) — kills the
// reduceM dispatch + gap.  2.1M fp32 atomics ~= 33 MB write-through (~5 us
// of BW), cheaper than 16 MB partials + 16 MB L3 reads + a dispatch.
// ---------------------------------------------------------------------------
__global__ __launch_bounds__(256) void k2_gemmM(const float* __restrict__ T,
                                                const float* __restrict__ inv_norm,
                                                float* __restrict__ Mt) {
    __shared__ _Float16 As[2][64][40];   // [buf][col][i]  10.2 KB
    __shared__ _Float16 Bs[2][64][40];   //                10.2 KB
    const int tid = threadIdx.x, bid = blockIdx.x;
    const int lane = tid & 63, wave = tid >> 6;

    // g in [0,512): (kx,dy,z) = (4,4,32), 256-row slab, 8 chunks of 32
    const int g = bid;
    const int k0 = (g & 3) * 64;
    const int d0 = ((g >> 2) & 3) * 64;
    const int i0 = (g >> 4) * 256;
    const int wy = wave >> 1, wx = wave & 1;      // 2x2 waves -> 32x32 each
    const int lm = lane & 15, lg = lane >> 4;
    const int i = tid & 31, c8 = (tid >> 5) * 8;  // stage map: row i, 8 cols
    f32x4 acc[2][2] = {};
    float4 rA[2], rB[2];
    float rI;

    auto stage = [&](int ic) {
        int gi = i0 + ic + i;
        rI = inv_norm[gi];
        const float* rowp = T + (size_t)gi * DIM;
        rA[0] = *(const float4*)(rowp + k0 + c8);
        rA[1] = *(const float4*)(rowp + k0 + c8 + 4);
        rB[0] = *(const float4*)(rowp + d0 + c8);
        rB[1] = *(const float4*)(rowp + d0 + c8 + 4);
    };
    auto commit = [&](int buf) {
#pragma unroll
        for (int j = 0; j < 2; ++j) {
            float4 a = rA[j], b = rB[j];
            int c = c8 + j * 4;
            As[buf][c + 0][i] = (_Float16)(a.x * rI);
            As[buf][c + 1][i] = (_Float16)(a.y * rI);
            As[buf][c + 2][i] = (_Float16)(a.z * rI);
            As[buf][c + 3][i] = (_Float16)(a.w * rI);
            Bs[buf][c + 0][i] = (_Float16)b.x;
            Bs[buf][c + 1][i] = (_Float16)b.y;
            Bs[buf][c + 2][i] = (_Float16)b.z;
            Bs[buf][c + 3][i] = (_Float16)b.w;
        }
    };
    auto compute = [&](int buf) {
        f16x8 af[2], bf[2];
#pragma unroll
        for (int mt = 0; mt < 2; ++mt)
            af[mt] = *(const f16x8*)&As[buf][wy * 32 + mt * 16 + lm][lg * 8];
#pragma unroll
        for (int nt = 0; nt < 2; ++nt)
            bf[nt] = *(const f16x8*)&Bs[buf][wx * 32 + nt * 16 + lm][lg * 8];
#pragma unroll
        for (int mt = 0; mt < 2; ++mt)
#pragma unroll
            for (int nt = 0; nt < 2; ++nt)
                acc[mt][nt] = __builtin_amdgcn_mfma_f32_16x16x32_f16(
                    af[mt], bf[nt], acc[mt][nt], 0, 0, 0);
    };

    stage(0);
    commit(0);
    __syncthreads();
    for (int c = 1; c < 8; ++c) {
        stage(c * 32);            // global loads for chunk c in flight
        compute((c - 1) & 1);     // MFMA on previous chunk
        commit(c & 1);            // write other buffer (no reader conflict)
        __syncthreads();          // ONE barrier per chunk
    }
    compute(1);

    // C/D frag: col = lane&15, row = (lane>>4)*4 + reg (r5/r10-verified).
    // Transposed atomic accumulate: Mt[d][k] += acc.
#pragma unroll
    for (int mt = 0; mt < 2; ++mt) {
        int km = k0 + wy * 32 + mt * 16 + lg * 4;
#pragma unroll
        for (int nt = 0; nt < 2; ++nt) {
            int dn = d0 + wx * 32 + nt * 16 + lm;
#pragma unroll
            for (int r = 0; r < 4; ++r)
                atomicAdd(&Mt[(size_t)dn * 256 + km + r], acc[mt][nt][r]);
        }
    }
}

// ---------------------------------------------------------------------------
// D3: out = diag(inv_rs) * Xhat * M via fp16 MFMA.  32x64 tiles, 1024
// blocks.  NEW (r14): each block computes inv_rs for its own 32 rows in an
// fp64 prologue (4x redundant across d-tiles — cheaper than a dispatch;
// fp64 math identical to the old rs kernel; VALU work co-schedules with
// MFMA, m114).  B staged from fp32 Mt rows (coalesced, L2-hot), converted
// to f16 at commit.
// ---------------------------------------------------------------------------
__global__ __launch_bounds__(256) void k3_mfma(const float* __restrict__ T,
                                               const float* __restrict__ inv_norm,
                                               const float* __restrict__ Mt,
                                               const double* __restrict__ s,
                                               float* __restrict__ out) {
    __shared__ _Float16 As[2][32][40];   // [buf][i][k]   5.1 KB
    __shared__ _Float16 Bs[2][64][40];   // [buf][d][k]  10.2 KB
    __shared__ float irs[32];
    const int tid = threadIdx.x, bid = blockIdx.x;
    const int lane = tid & 63, wave = tid >> 6;
    const int i0 = (bid >> 2) * 32;
    const int d0 = (bid & 3) * 64;
    const int wy = wave >> 1, wx = wave & 1;     // wave tile 16 x 32
    const int lm = lane & 15, lg = lane >> 4;
    f32x4 acc[2] = {};
    float4 rA;
    float rI;
    float4 rBf[2];
    const int ia = tid >> 3, c4 = (tid & 7) * 4;   // A: row ia, 4 k-cols
    const int db = tid >> 2, k8 = (tid & 3) * 8;   // B: row db, 8 k-cols

    auto stage = [&](int kc) {
        rI = inv_norm[i0 + ia];
        rA = *(const float4*)(T + (size_t)(i0 + ia) * DIM + kc + c4);
        const float* mp = Mt + (size_t)(d0 + db) * 256 + kc + k8;
        rBf[0] = *(const float4*)(mp);
        rBf[1] = *(const float4*)(mp + 4);
    };
    auto commit = [&](int buf) {
        As[buf][ia][c4 + 0] = (_Float16)(rA.x * rI);
        As[buf][ia][c4 + 1] = (_Float16)(rA.y * rI);
        As[buf][ia][c4 + 2] = (_Float16)(rA.z * rI);
        As[buf][ia][c4 + 3] = (_Float16)(rA.w * rI);
        f16x8 h;
        h[0] = (_Float16)rBf[0].x; h[1] = (_Float16)rBf[0].y;
        h[2] = (_Float16)rBf[0].z; h[3] = (_Float16)rBf[0].w;
        h[4] = (_Float16)rBf[1].x; h[5] = (_Float16)rBf[1].y;
        h[6] = (_Float16)rBf[1].z; h[7] = (_Float16)rBf[1].w;
        *(f16x8*)&Bs[buf][db][k8] = h;
    };
    auto compute = [&](int buf) {
        f16x8 af = *(const f16x8*)&As[buf][wy * 16 + lm][lg * 8];
        f16x8 bf0 = *(const f16x8*)&Bs[buf][wx * 32 + lm][lg * 8];
        f16x8 bf1 = *(const f16x8*)&Bs[buf][wx * 32 + 16 + lm][lg * 8];
        acc[0] = __builtin_amdgcn_mfma_f32_16x16x32_f16(af, bf0, acc[0], 0, 0, 0);
        acc[1] = __builtin_amdgcn_mfma_f32_16x16x32_f16(af, bf1, acc[1], 0, 0, 0);
    };

    stage(0);
    // ---- fp64 inv_rs prologue: wave handles 8 of the block's 32 rows.
    // (precision-critical: rs ~6e-4 possible from cancellation; fp64 keeps
    // rel err ~1e-9.  Loads are L3-hot; issued while stage(0) is in flight.)
    {
        const double s0 = s[lane * 4 + 0];
        const double s1 = s[lane * 4 + 1];
        const double s2 = s[lane * 4 + 2];
        const double s3 = s[lane * 4 + 3];
#pragma unroll
        for (int rr = 0; rr < 8; ++rr) {
            int row = i0 + wave * 8 + rr;
            float4 v = ((const float4*)(T + (size_t)row * DIM))[lane];
            double d = (double)v.x * s0 + (double)v.y * s1 +
                       (double)v.z * s2 + (double)v.w * s3;
#pragma unroll
            for (int o = 32; o; o >>= 1) d += __shfl_down(d, o);
            if (lane == 0)
                irs[wave * 8 + rr] = (float)(1.0 / (d * (double)inv_norm[row]));
        }
    }
    commit(0);
    __syncthreads();            // covers irs + buf0
    for (int c = 1; c < 8; ++c) {
        stage(c * 32);
        compute((c - 1) & 1);
        commit(c & 1);
        __syncthreads();
    }
    compute(1);

#pragma unroll
    for (int r = 0; r < 4; ++r) {
        int li = wy * 16 + lg * 4 + r;
        int gi = i0 + li;
        float ir = irs[li];
        out[(size_t)gi * DIM + d0 + wx * 32 + lm] = acc[0][r] * ir;
        out[(size_t)gi * DIM + d0 + wx * 32 + 16 + lm] = acc[1][r] * ir;
    }
}

// ---------------------------------------------------------------------------
extern "C" void kernel_launch(void* const* d_in, const int* in_sizes, int n_in,
                              void* d_out, int out_size, void* d_ws, size_t ws_size,
                              hipStream_t stream) {
    const float* T = (const float*)d_in[0];
    float* out = (float*)d_out;

    // workspace layout (16B-aligned, ~0.3 MB of 256 MiB):
    //   [0,       32768)   inv_norm  float[8192]
    //   [32768,   34816)   s         double[256]
    //   [34816,   296960)  Mt        float[256][256]  (M transposed, fp32)
    // s + Mt are contiguous -> ONE memset zeroes both.
    char* ws = (char*)d_ws;
    float* inv_norm = (float*)(ws);
    double* s = (double*)(ws + 32768);
    float* Mt = (float*)(ws + 34816);

    hipMemsetAsync(ws + 32768, 0, 264192, stream);   // s + Mt
    k1_norm<<<512, 256, 0, stream>>>(T, inv_norm, s);
    k2_gemmM<<<512, 256, 0, stream>>>(T, inv_norm, Mt);
    k3_mfma<<<1024, 256, 0, stream>>>(T, inv_norm, Mt, s, out);
}

// Round 15
// 94.435 us; speedup vs baseline: 1.3383x; 1.3383x over previous
//
#include <hip/hip_runtime.h>

#define N_ROWS 8192
#define DIM 256
#define EPSF 1e-8f

typedef _Float16 f16x8 __attribute__((ext_vector_type(8)));
typedef float f32x4 __attribute__((ext_vector_type(4)));

// ---------------------------------------------------------------------------
// D1: inv_norm (fp32) + fp64 column-sums of x_hat via LDS reduce + one
// f64 atomicAdd per thread (proven r1-r10).  512 blocks x 16 rows.
// ---------------------------------------------------------------------------
__global__ __launch_bounds__(256) void k1_norm(const float* __restrict__ T,
                                               float* __restrict__ inv_norm,
                                               double* __restrict__ s) {
    __shared__ double sacc[4][DIM];
    const int tid = threadIdx.x, bid = blockIdx.x;
    const int lane = tid & 63, wave = tid >> 6;
    double a0 = 0, a1 = 0, a2 = 0, a3 = 0;
#pragma unroll
    for (int r = 0; r < 4; ++r) {
        int row = bid * 16 + wave * 4 + r;
        float4 v = ((const float4*)(T + (size_t)row * DIM))[lane];
        float ss = v.x * v.x + v.y * v.y + v.z * v.z + v.w * v.w;
#pragma unroll
        for (int o = 32; o; o >>= 1) ss += __shfl_down(ss, o);
        ss = __shfl(ss, 0);
        float inv = 1.0f / fmaxf(sqrtf(ss), EPSF);
        if (lane == 0) inv_norm[row] = inv;
        a0 += (double)(v.x * inv);
        a1 += (double)(v.y * inv);
        a2 += (double)(v.z * inv);
        a3 += (double)(v.w * inv);
    }
    sacc[wave][lane * 4 + 0] = a0;
    sacc[wave][lane * 4 + 1] = a1;
    sacc[wave][lane * 4 + 2] = a2;
    sacc[wave][lane * 4 + 3] = a3;
    __syncthreads();
    double t = sacc[0][tid] + sacc[1][tid] + sacc[2][tid] + sacc[3][tid];
    atomicAdd(&s[tid], t);
}

// ---------------------------------------------------------------------------
// D2 (fused): blocks 0..511 = M-partials GEMM (fp16 MFMA, 64x64 tile,
// 256-row K-slab, double-buffered LDS, one barrier/chunk);
// blocks 512..2559 = inv_rs, ONE WAVE PER ROW (8192 independent waves).
// Long-running gemm role first so it starts first; rs waves backfill.
// (r14 lesson: do NOT replace partials with atomic Mt accumulation — 32-way
// per-address contention serializes; do NOT fold rs into k3's prologue —
// serial fp64 chains on the MFMA critical path.)
// ---------------------------------------------------------------------------
__global__ __launch_bounds__(256) void k2_gemm_rs(const float* __restrict__ T,
                                                  const float* __restrict__ inv_norm,
                                                  const double* __restrict__ s,
                                                  float* __restrict__ inv_rs,
                                                  float* __restrict__ partials) {
    __shared__ _Float16 As[2][64][40];   // [buf][col][i]  10.2 KB
    __shared__ _Float16 Bs[2][64][40];   //                10.2 KB
    const int tid = threadIdx.x, bid = blockIdx.x;
    const int lane = tid & 63, wave = tid >> 6;

    if (bid >= 512) {
        // ---- rs role: row = one wave.  fp64 dot (precision-critical:
        // rs ~6e-4 possible from cancellation; abs err budget ~1e-5).
        const int row = (bid - 512) * 4 + wave;
        const double s0 = s[lane * 4 + 0];
        const double s1 = s[lane * 4 + 1];
        const double s2 = s[lane * 4 + 2];
        const double s3 = s[lane * 4 + 3];
        float4 v = ((const float4*)(T + (size_t)row * DIM))[lane];
        double d = (double)v.x * s0 + (double)v.y * s1 +
                   (double)v.z * s2 + (double)v.w * s3;
#pragma unroll
        for (int o = 32; o; o >>= 1) d += __shfl_down(d, o);
        if (lane == 0)
            inv_rs[row] = (float)(1.0 / (d * (double)inv_norm[row]));
        return;
    }

    // ---- gemm role: g in [0,512): (kx,dy,z) = (4,4,32)
    const int g = bid;
    const int k0 = (g & 3) * 64;
    const int d0 = ((g >> 2) & 3) * 64;
    const int i0 = (g >> 4) * 256;
    const int wy = wave >> 1, wx = wave & 1;      // 2x2 waves -> 32x32 each
    const int lm = lane & 15, lg = lane >> 4;
    const int i = tid & 31, c8 = (tid >> 5) * 8;  // stage map: row i, 8 cols
    f32x4 acc[2][2] = {};
    float4 rA[2], rB[2];
    float rI;

    auto stage = [&](int ic) {
        int gi = i0 + ic + i;
        rI = inv_norm[gi];
        const float* rowp = T + (size_t)gi * DIM;
        rA[0] = *(const float4*)(rowp + k0 + c8);
        rA[1] = *(const float4*)(rowp + k0 + c8 + 4);
        rB[0] = *(const float4*)(rowp + d0 + c8);
        rB[1] = *(const float4*)(rowp + d0 + c8 + 4);
    };
    auto commit = [&](int buf) {
#pragma unroll
        for (int j = 0; j < 2; ++j) {
            float4 a = rA[j], b = rB[j];
            int c = c8 + j * 4;
            As[buf][c + 0][i] = (_Float16)(a.x * rI);
            As[buf][c + 1][i] = (_Float16)(a.y * rI);
            As[buf][c + 2][i] = (_Float16)(a.z * rI);
            As[buf][c + 3][i] = (_Float16)(a.w * rI);
            Bs[buf][c + 0][i] = (_Float16)b.x;
            Bs[buf][c + 1][i] = (_Float16)b.y;
            Bs[buf][c + 2][i] = (_Float16)b.z;
            Bs[buf][c + 3][i] = (_Float16)b.w;
        }
    };
    auto compute = [&](int buf) {
        f16x8 af[2], bf[2];
#pragma unroll
        for (int mt = 0; mt < 2; ++mt)
            af[mt] = *(const f16x8*)&As[buf][wy * 32 + mt * 16 + lm][lg * 8];
#pragma unroll
        for (int nt = 0; nt < 2; ++nt)
            bf[nt] = *(const f16x8*)&Bs[buf][wx * 32 + nt * 16 + lm][lg * 8];
#pragma unroll
        for (int mt = 0; mt < 2; ++mt)
#pragma unroll
            for (int nt = 0; nt < 2; ++nt)
                acc[mt][nt] = __builtin_amdgcn_mfma_f32_16x16x32_f16(
                    af[mt], bf[nt], acc[mt][nt], 0, 0, 0);
    };

    stage(0);
    commit(0);
    __syncthreads();
    for (int c = 1; c < 8; ++c) {
        stage(c * 32);            // global loads for chunk c in flight
        compute((c - 1) & 1);     // MFMA on previous chunk
        commit(c & 1);            // write other buffer (no reader conflict)
        __syncthreads();          // ONE barrier per chunk
    }
    compute(1);

    // C/D frag: col = lane&15, row = (lane>>4)*4 + reg (r5/r10-verified)
    float* pz = partials + (size_t)(g >> 4) * 65536;
#pragma unroll
    for (int mt = 0; mt < 2; ++mt) {
        int km = k0 + wy * 32 + mt * 16 + lg * 4;
#pragma unroll
        for (int nt = 0; nt < 2; ++nt) {
            int dn = d0 + wx * 32 + nt * 16 + lm;
#pragma unroll
            for (int r = 0; r < 4; ++r)
                pz[(size_t)(km + r) * 256 + dn] = acc[mt][nt][r];
        }
    }
}

// ---------------------------------------------------------------------------
// D3: reduce 32 partial slabs -> Mt (fp16, TRANSPOSED for k3's k-contiguous
// B loads).  Coalesced reads, 128 KB of writes.
// ---------------------------------------------------------------------------
__global__ __launch_bounds__(256) void k_reduceM(const float* __restrict__ partials,
                                                 _Float16* __restrict__ Mt) {
    const int gidx = blockIdx.x * 256 + threadIdx.x;
    const int k = gidx >> 8, d = gidx & 255;
    const float* p = partials + (size_t)k * 256 + d;
    float a0 = 0.f, a1 = 0.f, a2 = 0.f, a3 = 0.f;
#pragma unroll
    for (int z = 0; z < 32; z += 4) {
        a0 += p[(size_t)(z + 0) * 65536];
        a1 += p[(size_t)(z + 1) * 65536];
        a2 += p[(size_t)(z + 2) * 65536];
        a3 += p[(size_t)(z + 3) * 65536];
    }
    Mt[(size_t)d * 256 + k] = (_Float16)((a0 + a1) + (a2 + a3));
}

// ---------------------------------------------------------------------------
// D4: out = diag(inv_rs) * Xhat * M via fp16 MFMA.  32x64 tiles -> 1024
// blocks (4 blocks/CU), double-buffered LDS, one barrier per chunk.
// ---------------------------------------------------------------------------
__global__ __launch_bounds__(256) void k3_mfma(const float* __restrict__ T,
                                               const float* __restrict__ inv_norm,
                                               const _Float16* __restrict__ Mt,
                                               const float* __restrict__ inv_rs,
                                               float* __restrict__ out) {
    __shared__ _Float16 As[2][32][40];   // [buf][i][k]   5.1 KB
    __shared__ _Float16 Bs[2][64][40];   // [buf][d][k]  10.2 KB
    const int tid = threadIdx.x, bid = blockIdx.x;
    const int lane = tid & 63, wave = tid >> 6;
    const int i0 = (bid >> 2) * 32;
    const int d0 = (bid & 3) * 64;
    const int wy = wave >> 1, wx = wave & 1;     // wave tile 16 x 32
    const int lm = lane & 15, lg = lane >> 4;
    f32x4 acc[2] = {};
    float4 rA;
    float rI;
    f16x8 rB;
    const int ia = tid >> 3, c4 = (tid & 7) * 4;   // A: row ia, 4 k-cols
    const int db = tid >> 2, k8 = (tid & 3) * 8;   // B: row db, 8 k-cols

    auto stage = [&](int kc) {
        rI = inv_norm[i0 + ia];
        rA = *(const float4*)(T + (size_t)(i0 + ia) * DIM + kc + c4);
        rB = *(const f16x8*)(Mt + (size_t)(d0 + db) * 256 + kc + k8);
    };
    auto commit = [&](int buf) {
        As[buf][ia][c4 + 0] = (_Float16)(rA.x * rI);
        As[buf][ia][c4 + 1] = (_Float16)(rA.y * rI);
        As[buf][ia][c4 + 2] = (_Float16)(rA.z * rI);
        As[buf][ia][c4 + 3] = (_Float16)(rA.w * rI);
        *(f16x8*)&Bs[buf][db][k8] = rB;
    };
    auto compute = [&](int buf) {
        f16x8 af = *(const f16x8*)&As[buf][wy * 16 + lm][lg * 8];
        f16x8 bf0 = *(const f16x8*)&Bs[buf][wx * 32 + lm][lg * 8];
        f16x8 bf1 = *(const f16x8*)&Bs[buf][wx * 32 + 16 + lm][lg * 8];
        acc[0] = __builtin_amdgcn_mfma_f32_16x16x32_f16(af, bf0, acc[0], 0, 0, 0);
        acc[1] = __builtin_amdgcn_mfma_f32_16x16x32_f16(af, bf1, acc[1], 0, 0, 0);
    };

    stage(0);
    commit(0);
    __syncthreads();
    for (int c = 1; c < 8; ++c) {
        stage(c * 32);
        compute((c - 1) & 1);
        commit(c & 1);
        __syncthreads();
    }
    compute(1);

#pragma unroll
    for (int r = 0; r < 4; ++r) {
        int gi = i0 + wy * 16 + lg * 4 + r;
        float ir = inv_rs[gi];
        out[(size_t)gi * DIM + d0 + wx * 32 + lm] = acc[0][r] * ir;
        out[(size_t)gi * DIM + d0 + wx * 32 + 16 + lm] = acc[1][r] * ir;
    }
}

// ---------------------------------------------------------------------------
extern "C" void kernel_launch(void* const* d_in, const int* in_sizes, int n_in,
                              void* d_out, int out_size, void* d_ws, size_t ws_size,
                              hipStream_t stream) {
    const float* T = (const float*)d_in[0];
    float* out = (float*)d_out;

    // workspace layout (16B-aligned, ~8.5 MB of 256 MiB):
    //   [0,       32768)   inv_norm  float[8192]
    //   [32768,   34816)   s         double[256]
    //   [34816,   67584)   inv_rs    float[8192]
    //   [67584,   198656)  Mt        _Float16[256][256]  (M transposed)
    //   [198656,  +8 MiB)  partials  float[32][256][256]
    char* ws = (char*)d_ws;
    float* inv_norm = (float*)(ws);
    double* s = (double*)(ws + 32768);
    float* inv_rs = (float*)(ws + 34816);
    _Float16* Mt = (_Float16*)(ws + 67584);
    float* partials = (float*)(ws + 198656);

    hipMemsetAsync(s, 0, 256 * sizeof(double), stream);
    k1_norm<<<512, 256, 0, stream>>>(T, inv_norm, s);
    k2_gemm_rs<<<2560, 256, 0, stream>>>(T, inv_norm, s, inv_rs, partials);
    k_reduceM<<<256, 256, 0, stream>>>(partials, Mt);
    k3_mfma<<<1024, 256, 0, stream>>>(T, inv_norm, Mt, inv_rs, out);
}